// Round 1
// baseline (143.631 us; speedup 1.0000x reference)
//
#include <hip/hip_runtime.h>
#include <hip/hip_cooperative_groups.h>
#include <math.h>

namespace cg = cooperative_groups;

#define K_MAX 256
#define NB 256      // blocks (== K_MAX so phase 2 maps block b -> cluster b, and NB==NT)
#define NT 256      // threads per block

struct Ws {
    unsigned long long part_packed[NB * K_MAX]; // [block][k]  (q_bits<<32)|~idx
    unsigned int       part_beta[NB * K_MAX];   // [block][k]  beta-as-uint
    float              part_bg[NB];
    float              part_nb[NB];
    float4             cvec[K_MAX];             // (2q*ax, 2q*ay, 2q*az, q*(1-|a|^2))
    float              qv[K_MAX];               // q_ak
};

__device__ __forceinline__ float wave_sum(float v) {
    #pragma unroll
    for (int o = 32; o > 0; o >>= 1) v += __shfl_down(v, o, 64);
    return v;
}

// Single cooperative kernel: phase1 scan -> grid.sync -> phase2 reduce (+L_beta)
// -> grid.sync -> phase3 NxK potential. Replaces 3 dispatches with 1.
__global__ void __launch_bounds__(NT) k_fused(
        const float* __restrict__ x, const float* __restrict__ beta,
        const int* __restrict__ y, const int* __restrict__ Kp,
        const float* __restrict__ Sbp, const float* __restrict__ qminp,
        Ws* __restrict__ w, float* __restrict__ out, int N) {
    __shared__ unsigned long long s_u64[K_MAX];
    __shared__ unsigned int s_u32[K_MAX];
    __shared__ float4 s_c[K_MAX];
    __shared__ float s_q[K_MAX];
    __shared__ float s_w[8];
    const int t = threadIdx.x;
    const int b = blockIdx.x;
    const int lane = t & 63, wid = t >> 6;

    // ---------------- phase 1: privatized segment maxima + bg sums ----------------
    s_u64[t] = 0ULL;
    s_u32[t] = 0u;
    __syncthreads();
    const float qmin = qminp[0];
    float bg = 0.f, nbc = 0.f;
    for (int i = b * NT + t; i < N; i += NB * NT) {   // ~1.5 elements/thread, all 256 CUs
        float be = beta[i];
        int yi = y[i];
        if (yi < 0) { bg += be; nbc += 1.f; }
        else {
            atomicMax(&s_u32[yi], __float_as_uint(be));
            float a = atanhf(be);
            float q = fmaf(a, a, qmin);
            unsigned long long p = ((unsigned long long)__float_as_uint(q) << 32)
                                 | (unsigned long long)(~(unsigned int)i);
            atomicMax(&s_u64[yi], p);
        }
    }
    __syncthreads();
    w->part_packed[b * K_MAX + t] = s_u64[t];   // coalesced 2KB row per block
    w->part_beta[b * K_MAX + t]  = s_u32[t];
    {
        float r1 = wave_sum(bg), r2 = wave_sum(nbc);
        if (lane == 0) { s_w[wid] = r1; s_w[4 + wid] = r2; }
    }
    __syncthreads();
    if (t == 0) w->part_bg[b] = s_w[0] + s_w[1] + s_w[2] + s_w[3];
    if (t == 1) w->part_nb[b] = s_w[4] + s_w[5] + s_w[6] + s_w[7];
    if (b == 0 && t == 0) out[0] = 0.f;

    cg::this_grid().sync();

    // ---------------- phase 2: block b folds cluster b's NB partials ----------------
    {
        unsigned long long m = w->part_packed[t * K_MAX + b];   // NB == NT: one load/thread
        unsigned int bb = w->part_beta[t * K_MAX + b];
        #pragma unroll
        for (int o = 32; o > 0; o >>= 1) {
            unsigned long long v = __shfl_down(m, o, 64);  if (v > m)  m = v;
            unsigned int       u = __shfl_down(bb, o, 64); if (u > bb) bb = u;
        }
        if (lane == 0) { s_u64[wid] = m; s_u32[wid] = bb; }   // phase-1 reads done (grid.sync)
        __syncthreads();
        if (t == 0) {
            m = s_u64[0]; bb = s_u32[0];
            #pragma unroll
            for (int q2 = 1; q2 < NT / 64; ++q2) {
                if (s_u64[q2] > m)  m = s_u64[q2];
                if (s_u32[q2] > bb) bb = s_u32[q2];
            }
            float q; unsigned int idx;
            if (m == 0ULL) { q = 0.f; idx = 0u; }     // empty cluster -> q=0 -> uq=0 in phase 3
            else { q = __uint_as_float((unsigned int)(m >> 32)); idx = ~(unsigned int)m; }
            float ax = x[idx * 3], ay = x[idx * 3 + 1], az = x[idx * 3 + 2];
            w->cvec[b] = make_float4(2.f * q * ax, 2.f * q * ay, 2.f * q * az,
                                     q * (1.f - (ax * ax + ay * ay + az * az)));
            w->qv[b] = q;
            // L_beta cluster term folded here (was k_main block-0 epilogue)
            atomicAdd(out, (1.f - __uint_as_float(bb)) / (float)Kp[0]);
        }
        if (b == 0) {   // background term: reduce NB bg/nb partials (NB == NT)
            float r1 = wave_sum(w->part_bg[t]);
            float r2 = wave_sum(w->part_nb[t]);
            if (lane == 0) { s_w[wid] = r1; s_w[4 + wid] = r2; }
            __syncthreads();
            if (t == 0) {
                float bgt = s_w[0] + s_w[1] + s_w[2] + s_w[3];
                float nbt = s_w[4] + s_w[5] + s_w[6] + s_w[7];
                atomicAdd(out, Sbp[0] / nbt * bgt);
            }
        }
    }

    cg::this_grid().sync();

    // ---------------- phase 3: N x K potential ----------------
    s_c[t] = w->cvec[t];
    s_q[t] = w->qv[t];
    __syncthreads();
    float acc_t = 0.f;
    for (int i = b * NT + t; i < N; i += NB * NT) {
        float x0 = x[i * 3], x1 = x[i * 3 + 1], x2 = x[i * 3 + 2];
        float be = beta[i];
        int yi = y[i];
        float a = atanhf(be);
        float qi = fmaf(a, a, qmin);
        float negh = -(x0 * x0 + x1 * x1 + x2 * x2);
        float acc = 0.f;
        #pragma unroll 8
        for (int k = 0; k < K_MAX; ++k) {   // uq = q*(1-|x-a|^2) via 4 fma + max + add
            float4 c = s_c[k];
            float t0 = fmaf(s_q[k], negh, c.w);
            float uq = fmaf(c.x, x0, fmaf(c.y, x1, fmaf(c.z, x2, t0)));
            acc += fmaxf(uq, 0.f);
        }
        if (yi >= 0) {   // member: attractive q*d^2 replaces repulsive; q*d^2 = q - uq
            float4 c = s_c[yi];
            float qk = s_q[yi];
            float t0 = fmaf(qk, negh, c.w);
            float uq = fmaf(c.x, x0, fmaf(c.y, x1, fmaf(c.z, x2, t0)));
            acc += (qk - uq) - fmaxf(uq, 0.f);
        }
        acc_t += acc * qi;
    }
    float r = wave_sum(acc_t);
    __syncthreads();                  // guard s_w reuse (block 0 wrote it in phase 2)
    if (lane == 0) s_w[wid] = r;
    __syncthreads();
    if (t == 0) atomicAdd(out, (s_w[0] + s_w[1] + s_w[2] + s_w[3]) * (1.f / (float)N));
}

extern "C" void kernel_launch(void* const* d_in, const int* in_sizes, int n_in,
                              void* d_out, int out_size, void* d_ws, size_t ws_size,
                              hipStream_t stream) {
    const float* x     = (const float*)d_in[0];
    const float* beta  = (const float*)d_in[1];
    const int*   y     = (const int*)d_in[2];
    const int*   Kp    = (const int*)d_in[3];
    const float* Sbp   = (const float*)d_in[4];
    const float* qminp = (const float*)d_in[5];
    float* out = (float*)d_out;
    int N = in_sizes[1];
    Ws* w = (Ws*)d_ws;

    void* args[] = {(void*)&x, (void*)&beta, (void*)&y, (void*)&Kp,
                    (void*)&Sbp, (void*)&qminp, (void*)&w, (void*)&out, (void*)&N};
    hipLaunchCooperativeKernel((void*)k_fused, dim3(NB), dim3(NT), args, 0, stream);
}

// Round 2
// 81.593 us; speedup vs baseline: 1.7603x; 1.7603x over previous
//
#include <hip/hip_runtime.h>
#include <math.h>

#define K_MAX 256
#define NB 256     // stage-1 blocks (widened 64 -> 256: all CUs; logic harness-verified in r1)
#define NT 256

struct Ws {
    unsigned long long part_packed[NB * K_MAX]; // [block][k]  (q_bits<<32)|~idx
    unsigned int       part_beta[NB * K_MAX];   // [block][k]  beta-as-uint
    float              part_bg[NB];
    float              part_nb[NB];
    float4             cvec[K_MAX];             // (2q*ax, 2q*ay, 2q*az, q*(1-|a|^2))
    float              qv[K_MAX];               // q_ak
    float              bak[K_MAX];              // 1 - beta_ak
    float              bg_total;
    float              nb_total;
};

__device__ __forceinline__ float wave_sum(float v) {
    #pragma unroll
    for (int o = 32; o > 0; o >>= 1) v += __shfl_down(v, o, 64);
    return v;
}

// Stage 1: privatized per-block segment maxima in LDS, coalesced stores out.
__global__ void __launch_bounds__(NT) k_scan(const float* __restrict__ beta,
        const int* __restrict__ y, const float* __restrict__ qminp,
        Ws* __restrict__ w, int N) {
    __shared__ unsigned long long s_u64[K_MAX];
    __shared__ unsigned int s_u32[K_MAX];
    __shared__ float s_w[8];
    int t = threadIdx.x;
    int b = blockIdx.x;
    s_u64[t] = 0ULL;
    s_u32[t] = 0u;
    __syncthreads();
    float qmin = qminp[0];
    float bg = 0.f, nbc = 0.f;
    for (int i = b * NT + t; i < N; i += NB * NT) {   // ~1.5 elems/thread across 256 CUs
        float be = beta[i];
        int yi = y[i];
        if (yi < 0) { bg += be; nbc += 1.f; }
        else {
            atomicMax(&s_u32[yi], __float_as_uint(be));
            float a = atanhf(be);
            float q = fmaf(a, a, qmin);
            unsigned long long p = ((unsigned long long)__float_as_uint(q) << 32)
                                 | (unsigned long long)(~(unsigned int)i);
            atomicMax(&s_u64[yi], p);
        }
    }
    __syncthreads();
    w->part_packed[b * K_MAX + t] = s_u64[t];
    w->part_beta[b * K_MAX + t]  = s_u32[t];
    int lane = t & 63, wid = t >> 6;
    float r1 = wave_sum(bg);
    float r2 = wave_sum(nbc);
    if (lane == 0) { s_w[wid] = r1; s_w[4 + wid] = r2; }
    __syncthreads();
    if (t == 0) w->part_bg[b] = s_w[0] + s_w[1] + s_w[2] + s_w[3];
    if (t == 1) w->part_nb[b] = s_w[4] + s_w[5] + s_w[6] + s_w[7];
}

// Stage 2: block k (256 threads) folds cluster k's 256 partials;
// blocks 256/257 fold bg/nb; block 256 also zero-inits out[0].
__global__ void __launch_bounds__(NT) k_reduce(const float* __restrict__ x,
        Ws* __restrict__ w, float* __restrict__ out) {
    __shared__ unsigned long long s_u64[4];
    __shared__ unsigned int s_u32[4];
    __shared__ float s_w[4];
    int b = blockIdx.x, t = threadIdx.x;
    int lane = t & 63, wid = t >> 6;
    if (b < K_MAX) {
        unsigned long long m = w->part_packed[t * K_MAX + b];   // NB == NT: one load/thread
        unsigned int bb = w->part_beta[t * K_MAX + b];
        #pragma unroll
        for (int o = 32; o > 0; o >>= 1) {
            unsigned long long v = __shfl_down(m, o, 64);  if (v > m)  m = v;
            unsigned int       u = __shfl_down(bb, o, 64); if (u > bb) bb = u;
        }
        if (lane == 0) { s_u64[wid] = m; s_u32[wid] = bb; }
        __syncthreads();
        if (t == 0) {
            m = s_u64[0]; bb = s_u32[0];
            #pragma unroll
            for (int q2 = 1; q2 < NT / 64; ++q2) {
                if (s_u64[q2] > m)  m = s_u64[q2];
                if (s_u32[q2] > bb) bb = s_u32[q2];
            }
            float q; unsigned int idx;
            if (m == 0ULL) { q = 0.f; idx = 0u; }   // empty cluster -> q=0 -> uq=0 in stage 3
            else { q = __uint_as_float((unsigned int)(m >> 32)); idx = ~(unsigned int)m; }
            float ax = x[idx * 3], ay = x[idx * 3 + 1], az = x[idx * 3 + 2];
            w->cvec[b] = make_float4(2.f * q * ax, 2.f * q * ay, 2.f * q * az,
                                     q * (1.f - (ax * ax + ay * ay + az * az)));
            w->qv[b]  = q;
            w->bak[b] = 1.f - __uint_as_float(bb);
        }
    } else {
        const float* src = (b == K_MAX) ? w->part_bg : w->part_nb;
        float s = wave_sum(src[t]);
        if (lane == 0) s_w[wid] = s;
        __syncthreads();
        if (t == 0) {
            float tot = s_w[0] + s_w[1] + s_w[2] + s_w[3];
            if (b == K_MAX) { w->bg_total = tot; out[0] = 0.f; }
            else            { w->nb_total = tot; }
        }
    }
}

// Stage 3: N x K potential. uq = q*(1-|x-a|^2) via premultiplied coeffs:
// uq = c.x*x0 + c.y*x1 + c.z*x2 + q*(-h) + c.w   (4 fma + max + add per k).
// Block 0 also folds L_beta into out.
__global__ void __launch_bounds__(NT) k_main(const float* __restrict__ x,
        const float* __restrict__ beta, const int* __restrict__ y,
        const int* __restrict__ Kp, const float* __restrict__ Sbp,
        const float* __restrict__ qminp, const Ws* __restrict__ w,
        float* __restrict__ out, int N) {
    __shared__ float4 s_c[K_MAX];
    __shared__ float s_q[K_MAX];
    __shared__ float s_w[8];
    int t = threadIdx.x;
    s_c[t] = w->cvec[t];
    s_q[t] = w->qv[t];
    __syncthreads();
    int i = blockIdx.x * NT + t;
    float contrib = 0.f;
    if (i < N) {
        float x0 = x[i * 3], x1 = x[i * 3 + 1], x2 = x[i * 3 + 2];
        float be = beta[i];
        int yi = y[i];
        float a = atanhf(be);
        float qi = fmaf(a, a, qminp[0]);
        float negh = -(x0 * x0 + x1 * x1 + x2 * x2);
        float acc = 0.f;
        #pragma unroll 8
        for (int k = 0; k < K_MAX; ++k) {     // empty/out-of-range clusters have q=0 -> uq=0
            float4 c = s_c[k];
            float t0 = fmaf(s_q[k], negh, c.w);
            float uq = fmaf(c.x, x0, fmaf(c.y, x1, fmaf(c.z, x2, t0)));
            acc += fmaxf(uq, 0.f);
        }
        if (yi >= 0) {   // member: attractive q*d^2 replaces repulsive; q*d^2 = q - uq
            float4 c = s_c[yi];
            float qk = s_q[yi];
            float t0 = fmaf(qk, negh, c.w);
            float uq = fmaf(c.x, x0, fmaf(c.y, x1, fmaf(c.z, x2, t0)));
            acc += (qk - uq) - fmaxf(uq, 0.f);
        }
        contrib = acc * qi;
    }
    int lane = t & 63, wid = t >> 6;
    float r = wave_sum(contrib);
    if (lane == 0) s_w[wid] = r;
    __syncthreads();
    if (t == 0) atomicAdd(out, (s_w[0] + s_w[1] + s_w[2] + s_w[3]) * (1.f / (float)N));
    if (blockIdx.x == 0) {
        int K = Kp[0];
        float v = wave_sum((t < K) ? w->bak[t] : 0.f);
        if (lane == 0) s_w[4 + wid] = v;
        __syncthreads();
        if (t == 0) {
            float sb = s_w[4] + s_w[5] + s_w[6] + s_w[7];
            atomicAdd(out, sb / (float)K + Sbp[0] / w->nb_total * w->bg_total);
        }
    }
}

extern "C" void kernel_launch(void* const* d_in, const int* in_sizes, int n_in,
                              void* d_out, int out_size, void* d_ws, size_t ws_size,
                              hipStream_t stream) {
    const float* x     = (const float*)d_in[0];
    const float* beta  = (const float*)d_in[1];
    const int*   y     = (const int*)d_in[2];
    const int*   Kp    = (const int*)d_in[3];
    const float* Sbp   = (const float*)d_in[4];
    const float* qminp = (const float*)d_in[5];
    float* out = (float*)d_out;
    int N = in_sizes[1];
    Ws* w = (Ws*)d_ws;
    int nb = (N + NT - 1) / NT;

    k_scan<<<NB, NT, 0, stream>>>(beta, y, qminp, w, N);
    k_reduce<<<K_MAX + 2, NT, 0, stream>>>(x, w, out);
    k_main<<<nb, NT, 0, stream>>>(x, beta, y, Kp, Sbp, qminp, w, out, N);
}